// Round 7
// baseline (5058.153 us; speedup 1.0000x reference)
//
#include <hip/hip_runtime.h>
#include <hip/hip_bf16.h>

#define B_ 256
#define S_ 2048
#define D_ 16
#define H_ 128

typedef unsigned int u32;
typedef unsigned short u16;
typedef _Float16 h2t __attribute__((ext_vector_type(2)));

// ---- output layout (flat f32): returns | volatility | hidden_h | hidden_c
#define RET0 ((size_t)0)
#define VOL0 ((size_t)524288)
#define HH0  ((size_t)1048576)
#define HC0  ((size_t)1114112)

__device__ __forceinline__ float fdot2(u32 a, u32 b, float c) {
    return __builtin_amdgcn_fdot2(__builtin_bit_cast(h2t, a),
                                  __builtin_bit_cast(h2t, b), c, false);
}
__device__ __forceinline__ u32 packh2(float a, float b) {
    h2t h; h[0] = (_Float16)a; h[1] = (_Float16)b;
    return __builtin_bit_cast(u32, h);
}
__device__ __forceinline__ float sigm(float x) {
    return __builtin_amdgcn_rcpf(1.f + __builtin_amdgcn_exp2f(-1.44269504f * x));
}
__device__ __forceinline__ float tanh_(float x) {
    return 2.f * __builtin_amdgcn_rcpf(1.f + __builtin_amdgcn_exp2f(-2.88539008f * x)) - 1.f;
}
__device__ __forceinline__ float softplus_(float x) {
    if (x > 20.f) return x;
    const float e = __builtin_amdgcn_exp2f(1.44269504f * x);
    return 0.69314718f * __builtin_amdgcn_logf(1.f + e);  // v_log_f32 is log2
}

// ===================== layer 0 ==============================================
// 1024 thr: tid = m*8 + g*2 + k0. Each thread: one gate row, one K-half.
// K = [x(16) | h1(128)] = 72 pairs; k0=0 -> pairs 0..35 (x:0..7, h:8..35),
// k0=1 -> pairs 36..71 (h pairs 28..63). 36 weight regs/thread.
__global__ __launch_bounds__(1024, 4) void k_l0(
    const float* __restrict__ x, const float* __restrict__ Wih,
    const float* __restrict__ Whh, const float* __restrict__ bih,
    const float* __restrict__ bhh, u32* __restrict__ h1out,
    float* __restrict__ out)
{
    __shared__ u32 xp2[2][4096];   // 512-step x window, f16 pairs (32KB)
    __shared__ u32 hb[2][64];      // h1 state double buffer (f16 pairs)
    __shared__ u32 och[4096];      // 64-step h1 output staging (16KB)

    const int tid = threadIdx.x, b = blockIdx.x;
    const int m = tid >> 3, g = (tid >> 1) & 3, k0 = tid & 1;
    const int row = g * H_ + m;

    // ---- weights: uniform 18x float4 via per-lane pointers
    u32 w[36];
    {
        const float* p1 = k0 ? (Whh + row * H_ + 56) : (Wih + row * D_);
        const float* p2 = k0 ? (Whh + row * H_ + 72) : (Whh + row * H_);
#pragma unroll
        for (int j = 0; j < 4; ++j) {
            const float4 f = ((const float4*)p1)[j];
            w[2 * j] = packh2(f.x, f.y); w[2 * j + 1] = packh2(f.z, f.w);
        }
#pragma unroll
        for (int j = 0; j < 14; ++j) {
            const float4 f = ((const float4*)p2)[j];
            w[8 + 2 * j] = packh2(f.x, f.y); w[9 + 2 * j] = packh2(f.z, f.w);
        }
    }
    const float bs = k0 ? 0.f : (bih[row] + bhh[row]);

    const float* xb = x + (size_t)b * S_ * D_;
    for (int i = tid; i < 2048; i += 1024) {     // stage window 0
        const float4 v = *(const float4*)(xb + i * 4);
        xp2[0][2 * i] = packh2(v.x, v.y);
        xp2[0][2 * i + 1] = packh2(v.z, v.w);
    }
    if (tid < 128) ((u32*)hb)[tid] = 0u;
    float c = 0.f;
    __syncthreads();

    for (int t = 0; t < S_; ++t) {
        if ((t & 511) == 0 && t < S_ - 512) {    // prefetch next x window
            const int nw = (t >> 9) + 1;
            u32* dst = xp2[nw & 1];
            const float* src = xb + (size_t)nw * 8192;
            for (int i = tid; i < 2048; i += 1024) {
                const float4 v = *(const float4*)(src + i * 4);
                dst[2 * i] = packh2(v.x, v.y);
                dst[2 * i + 1] = packh2(v.z, v.w);
            }
        }
        const u32* hprev = hb[(t + 1) & 1];
        const u32* xslot = &xp2[(t >> 9) & 1][(t & 511) * 8];
        const uint4* pA = (const uint4*)(k0 ? hprev + 28 : xslot);
        const uint4* pB = (const uint4*)(k0 ? hprev + 36 : hprev);

        float a0 = bs, a1 = 0.f, a2 = 0.f, a3 = 0.f;
        {
            const uint4 v0 = pA[0], v1 = pA[1];
            a0 = fdot2(v0.x, w[0], a0); a1 = fdot2(v0.y, w[1], a1);
            a2 = fdot2(v0.z, w[2], a2); a3 = fdot2(v0.w, w[3], a3);
            a0 = fdot2(v1.x, w[4], a0); a1 = fdot2(v1.y, w[5], a1);
            a2 = fdot2(v1.z, w[6], a2); a3 = fdot2(v1.w, w[7], a3);
        }
#pragma unroll
        for (int p = 0; p < 7; ++p) {
            const uint4 v = pB[p];
            a0 = fdot2(v.x, w[8 + 4 * p], a0); a1 = fdot2(v.y, w[9 + 4 * p], a1);
            a2 = fdot2(v.z, w[10 + 4 * p], a2); a3 = fdot2(v.w, w[11 + 4 * p], a3);
        }
        float a = (a0 + a1) + (a2 + a3);
        a += __shfl_xor(a, 1);                   // combine K-halves
        const float af = __shfl_down(a, 2);      // gate f
        const float ag = __shfl_down(a, 4);      // gate g
        const float ao = __shfl_down(a, 6);      // gate o
        float hv = 0.f;
        if ((tid & 7) == 0) {                    // designated unit lane
            const float ig = sigm(a), fg = sigm(af);
            const float gc = tanh_(ag), og = sigm(ao);
            c = fg * c + ig * gc;
            hv = og * tanh_(c);
        }
        const float hnb = __shfl_down(hv, 8);
        if ((tid & 15) == 0) {                   // pack unit pair (m, m+1)
            const u32 pp = packh2(hv, hnb);
            hb[t & 1][m >> 1] = pp;
            och[(t & 63) * 64 + (m >> 1)] = pp;
        }
        if (t == S_ - 1 && (tid & 7) == 0) {
            out[HH0 + (size_t)b * H_ + m] = hv;
            out[HC0 + (size_t)b * H_ + m] = c;
        }
        __syncthreads();
        if ((t & 63) == 63) {                    // flush 64 h1 rows
            u32* dst = h1out + ((size_t)b * S_ + (t - 63)) * 64;
            *(uint4*)(dst + tid * 4) = *(const uint4*)(&och[tid * 4]);
            __syncthreads();
        }
    }
}

// ===================== layer 1 ==============================================
// Same layout. K = [h1(128) | h2(128)]: k0=0 -> W_ih·h1, k0=1 -> W_hh·h2.
// 64 weight regs/thread. h2 pairs overwrite consumed h1 rows in ws.
__global__ __launch_bounds__(1024, 4) void k_l1(
    u32* __restrict__ hws,
    const float* __restrict__ Wih, const float* __restrict__ Whh,
    const float* __restrict__ bih, const float* __restrict__ bhh,
    float* __restrict__ out)
{
    __shared__ u32 h1w[8192];      // 128-step h1 window (32KB)
    __shared__ u32 hp[2][64];      // h2 state double buffer
    __shared__ u32 och[4096];      // 64-step h2 staging (16KB)

    const int tid = threadIdx.x, b = blockIdx.x;
    const int m = tid >> 3, g = (tid >> 1) & 3, k0 = tid & 1;
    const int row = g * H_ + m;

    u32 w[64];
    {
        const float4* ws_ = (const float4*)((k0 ? Whh : Wih) + row * H_);
#pragma unroll
        for (int j = 0; j < 32; ++j) {
            const float4 f = ws_[j];
            w[2 * j] = packh2(f.x, f.y); w[2 * j + 1] = packh2(f.z, f.w);
        }
    }
    const float bs = k0 ? 0.f : (bih[row] + bhh[row]);

    if (tid < 128) ((u32*)hp)[tid] = 0u;
    float c = 0.f;
    __syncthreads();

    u32* hbase = hws + (size_t)b * S_ * 64;
    for (int u = 0; u < S_; ++u) {
        if ((u & 127) == 0) {                    // stage 128-step h1 window
            for (int i = tid; i < 2048; i += 1024)
                *(uint4*)(&h1w[i * 4]) = *(const uint4*)(hbase + (size_t)u * 64 + i * 4);
            __syncthreads();
        }
        const uint4* src = (const uint4*)(k0 ? hp[(u + 1) & 1] : &h1w[(u & 127) * 64]);
        float a0 = bs, a1 = 0.f, a2 = 0.f, a3 = 0.f;
#pragma unroll
        for (int p = 0; p < 16; ++p) {
            const uint4 v = src[p];
            a0 = fdot2(v.x, w[4 * p], a0); a1 = fdot2(v.y, w[4 * p + 1], a1);
            a2 = fdot2(v.z, w[4 * p + 2], a2); a3 = fdot2(v.w, w[4 * p + 3], a3);
        }
        float a = (a0 + a1) + (a2 + a3);
        a += __shfl_xor(a, 1);
        const float af = __shfl_down(a, 2);
        const float ag = __shfl_down(a, 4);
        const float ao = __shfl_down(a, 6);
        float hv = 0.f;
        if ((tid & 7) == 0) {
            const float ig = sigm(a), fg = sigm(af);
            const float gc = tanh_(ag), og = sigm(ao);
            c = fg * c + ig * gc;
            hv = og * tanh_(c);
        }
        const float hnb = __shfl_down(hv, 8);
        if ((tid & 15) == 0) {
            const u32 pp = packh2(hv, hnb);
            hp[u & 1][m >> 1] = pp;
            och[(u & 63) * 64 + (m >> 1)] = pp;
        }
        if (u == S_ - 1 && (tid & 7) == 0) {
            out[HH0 + 32768 + (size_t)b * H_ + m] = hv;
            out[HC0 + 32768 + (size_t)b * H_ + m] = c;
        }
        __syncthreads();
        if ((u & 63) == 63) {                    // flush h2 rows (in-place)
            u32* dst = hbase + (size_t)(u - 63) * 64;
            *(uint4*)(dst + tid * 4) = *(const uint4*)(&och[tid * 4]);
            __syncthreads();
        }
    }
}

// ===================== heads: parallel over (b,s) ===========================
__global__ __launch_bounds__(256) void k_heads(
    const u32* __restrict__ h2p,
    const float* __restrict__ Wr1, const float* __restrict__ br1,
    const float* __restrict__ Wr2, const float* __restrict__ br2,
    const float* __restrict__ Wv1, const float* __restrict__ bv1,
    const float* __restrict__ Wv2, const float* __restrict__ bv2,
    float* __restrict__ out)
{
    __shared__ u32 wr[64 * 64], wv[64 * 64];   // W1 pairs (16KB each)
    __shared__ float w2r[64], w2v[64], b1r[64], b1v[64];

    const int tid = threadIdx.x;
    for (int i = tid; i < 4096; i += 256) {
        wr[i] = packh2(Wr1[2 * i], Wr1[2 * i + 1]);
        wv[i] = packh2(Wv1[2 * i], Wv1[2 * i + 1]);
    }
    if (tid < 64) {
        w2r[tid] = Wr2[tid]; w2v[tid] = Wv2[tid];
        b1r[tid] = br1[tid]; b1v[tid] = bv1[tid];
    }
    __syncthreads();

    const size_t bs = (size_t)blockIdx.x * 256 + tid;   // (b,s) flat
    u32 hq[64];
    const u32* src = h2p + bs * 64;
#pragma unroll
    for (int j4 = 0; j4 < 16; ++j4) {
        const uint4 v = *(const uint4*)(src + j4 * 4);
        hq[j4 * 4] = v.x; hq[j4 * 4 + 1] = v.y; hq[j4 * 4 + 2] = v.z; hq[j4 * 4 + 3] = v.w;
    }
    float ret = br2[0], vol = bv2[0];
    for (int k = 0; k < 64; ++k) {
        float r = b1r[k], v = b1v[k];
#pragma unroll
        for (int j = 0; j < 64; ++j) r = fdot2(hq[j], wr[k * 64 + j], r);
#pragma unroll
        for (int j = 0; j < 64; ++j) v = fdot2(hq[j], wv[k * 64 + j], v);
        r = r > 0.f ? r : 0.01f * r;
        v = v > 0.f ? v : 0.01f * v;
        ret += r * w2r[k];
        vol += v * w2v[k];
    }
    out[RET0 + bs] = ret;
    out[VOL0 + bs] = softplus_(vol);
}

extern "C" void kernel_launch(void* const* d_in, const int* in_sizes, int n_in,
                              void* d_out, int out_size, void* d_ws, size_t ws_size,
                              hipStream_t stream) {
    (void)in_sizes; (void)n_in; (void)out_size; (void)ws_size;
    const float* x    = (const float*)d_in[0];
    const float* Wih0 = (const float*)d_in[1];
    const float* Whh0 = (const float*)d_in[2];
    const float* bih0 = (const float*)d_in[3];
    const float* bhh0 = (const float*)d_in[4];
    const float* Wih1 = (const float*)d_in[5];
    const float* Whh1 = (const float*)d_in[6];
    const float* bih1 = (const float*)d_in[7];
    const float* bhh1 = (const float*)d_in[8];
    const float* Wr1  = (const float*)d_in[9];
    const float* br1  = (const float*)d_in[10];
    const float* Wr2  = (const float*)d_in[11];
    const float* br2  = (const float*)d_in[12];
    const float* Wv1  = (const float*)d_in[13];
    const float* bv1  = (const float*)d_in[14];
    const float* Wv2  = (const float*)d_in[15];
    const float* bv2  = (const float*)d_in[16];
    u32* hws = (u32*)d_ws;            // 256*2048*64 u32 = 134MB (h1, then h2 in-place)
    float* out = (float*)d_out;

    k_l0<<<B_, 1024, 0, stream>>>(x, Wih0, Whh0, bih0, bhh0, hws, out);
    k_l1<<<B_, 1024, 0, stream>>>(hws, Wih1, Whh1, bih1, bhh1, out);
    k_heads<<<2048, 256, 0, stream>>>(hws, Wr1, br1, Wr2, br2, Wv1, bv1, Wv2, bv2, out);
}

// Round 8
// 4170.404 us; speedup vs baseline: 1.2129x; 1.2129x over previous
//
#include <hip/hip_runtime.h>
#include <hip/hip_bf16.h>

#define B_ 256
#define S_ 2048
#define D_ 16
#define H_ 128

typedef unsigned int u32;
typedef unsigned short u16;
typedef _Float16 h2t __attribute__((ext_vector_type(2)));

// ---- output layout (flat f32): returns | volatility | hidden_h | hidden_c
#define RET0 ((size_t)0)
#define VOL0 ((size_t)524288)
#define HH0  ((size_t)1048576)
#define HC0  ((size_t)1114112)

__device__ __forceinline__ float fdot2(u32 a, u32 b, float c) {
    return __builtin_amdgcn_fdot2(__builtin_bit_cast(h2t, a),
                                  __builtin_bit_cast(h2t, b), c, false);
}
__device__ __forceinline__ u32 packh2(float a, float b) {
    h2t h; h[0] = (_Float16)a; h[1] = (_Float16)b;
    return __builtin_bit_cast(u32, h);
}
__device__ __forceinline__ float sigm(float x) {
    return __builtin_amdgcn_rcpf(1.f + __builtin_amdgcn_exp2f(-1.44269504f * x));
}
__device__ __forceinline__ float tanh_(float x) {
    return 2.f * __builtin_amdgcn_rcpf(1.f + __builtin_amdgcn_exp2f(-2.88539008f * x)) - 1.f;
}
__device__ __forceinline__ float softplus_(float x) {
    if (x > 20.f) return x;
    const float e = __builtin_amdgcn_exp2f(1.44269504f * x);
    return 0.69314718f * __builtin_amdgcn_logf(1.f + e);  // v_log_f32 is log2
}
// cross-lane reduction helpers: xor1/xor2 = DPP quad_perm (VALU), xor4 = ds_swizzle
__device__ __forceinline__ float dxor1(float a) {
    return __builtin_bit_cast(float, __builtin_amdgcn_update_dpp(
        0, __builtin_bit_cast(int, a), 0xB1, 0xF, 0xF, true));   // [1,0,3,2]
}
__device__ __forceinline__ float dxor2(float a) {
    return __builtin_bit_cast(float, __builtin_amdgcn_update_dpp(
        0, __builtin_bit_cast(int, a), 0x4E, 0xF, 0xF, true));   // [2,3,0,1]
}
__device__ __forceinline__ float sxor4(float a) {
    return __builtin_bit_cast(float, __builtin_amdgcn_ds_swizzle(
        __builtin_bit_cast(int, a), 0x101F));                    // lane ^= 4
}
#define REDUCE8(a) { a += dxor1(a); a += dxor2(a); a += sxor4(a); }

// ===================== layer 0 ==============================================
// 1024 thr: tid = m*8 + ksl. Thread: all 4 gates of unit m over K-eighth ksl.
// K = [x pair ksl (1)] + [h pairs 8ksl..8ksl+8). 36 weight u32/thread.
__global__ __launch_bounds__(1024, 4) void k_l0(
    const float* __restrict__ x, const float* __restrict__ Wih,
    const float* __restrict__ Whh, const float* __restrict__ bih,
    const float* __restrict__ bhh, u32* __restrict__ h1out,
    float* __restrict__ out)
{
    __shared__ u32 xp2[2][4096];   // 512-step x window, f16 pairs (32KB)
    __shared__ u32 hb[2][64];      // h1 state double buffer (f16 pairs)
    __shared__ u32 och[4096];      // 64-step h1 output staging (16KB)

    const int tid = threadIdx.x, b = blockIdx.x;
    const int m = tid >> 3, ksl = tid & 7;

    u32 wx[4], wh[32];
    float bias[4];
#pragma unroll
    for (int g = 0; g < 4; ++g) {
        const int row = g * H_ + m;
        const float2 f2 = *(const float2*)(Wih + row * D_ + ksl * 2);
        wx[g] = packh2(f2.x, f2.y);
        const float4* whr = (const float4*)(Whh + row * H_ + ksl * 16);
#pragma unroll
        for (int j = 0; j < 4; ++j) {
            const float4 f = whr[j];
            wh[g * 8 + 2 * j]     = packh2(f.x, f.y);
            wh[g * 8 + 2 * j + 1] = packh2(f.z, f.w);
        }
        bias[g] = bih[row] + bhh[row];
    }

    const float* xb = x + (size_t)b * S_ * D_;
    for (int i = tid; i < 2048; i += 1024) {     // stage window 0
        const float4 v = *(const float4*)(xb + i * 4);
        xp2[0][2 * i] = packh2(v.x, v.y);
        xp2[0][2 * i + 1] = packh2(v.z, v.w);
    }
    if (tid < 128) ((u32*)hb)[tid] = 0u;
    float c = 0.f;
    __syncthreads();

    for (int t = 0; t < S_; ++t) {
        if ((t & 511) == 0 && t < S_ - 512) {    // prefetch next x window
            const int nw = (t >> 9) + 1;
            u32* dst = xp2[nw & 1];
            const float* src = xb + (size_t)nw * 8192;
            for (int i = tid; i < 2048; i += 1024) {
                const float4 v = *(const float4*)(src + i * 4);
                dst[2 * i] = packh2(v.x, v.y);
                dst[2 * i + 1] = packh2(v.z, v.w);
            }
        }
        const u32 xv = xp2[(t >> 9) & 1][(t & 511) * 8 + ksl];
        const u32* hsel = &hb[(t + 1) & 1][ksl * 8];
        const uint4 h0 = *(const uint4*)(hsel);
        const uint4 h1v = *(const uint4*)(hsel + 4);

        float a0 = fdot2(xv, wx[0], 0.f), a1 = fdot2(xv, wx[1], 0.f);
        float a2 = fdot2(xv, wx[2], 0.f), a3 = fdot2(xv, wx[3], 0.f);
#define L0G(comp, j)                                                           \
        a0 = fdot2(comp, wh[j], a0);      a1 = fdot2(comp, wh[8 + (j)], a1);   \
        a2 = fdot2(comp, wh[16 + (j)], a2); a3 = fdot2(comp, wh[24 + (j)], a3);
        L0G(h0.x, 0) L0G(h0.y, 1) L0G(h0.z, 2) L0G(h0.w, 3)
        L0G(h1v.x, 4) L0G(h1v.y, 5) L0G(h1v.z, 6) L0G(h1v.w, 7)
#undef L0G
        REDUCE8(a0) REDUCE8(a1) REDUCE8(a2) REDUCE8(a3)
        // all 8 lanes of the unit redundantly compute the cell update
        const float ig = sigm(a0 + bias[0]);
        const float fg = sigm(a1 + bias[1]);
        const float gc = tanh_(a2 + bias[2]);
        const float og = sigm(a3 + bias[3]);
        c = fg * c + ig * gc;
        const float hv = og * tanh_(c);
        const u32 pp = packh2(hv, __shfl_xor(hv, 8));
        if ((tid & 15) == 0) {                   // ksl==0 && m even
            hb[t & 1][m >> 1] = pp;
            och[(t & 63) * 64 + (m >> 1)] = pp;
        }
        if (t == S_ - 1 && (tid & 7) == 0) {
            out[HH0 + (size_t)b * H_ + m] = hv;
            out[HC0 + (size_t)b * H_ + m] = c;
        }
        __syncthreads();
        if ((t & 63) == 63) {                    // flush 64 h1 rows
            u32* dst = h1out + ((size_t)b * S_ + (t - 63)) * 64;
            *(uint4*)(dst + tid * 4) = *(const uint4*)(&och[tid * 4]);
            __syncthreads();
        }
    }
}

// ===================== layer 1 ==============================================
// tid = m*8 + ksl. K = [h1: chunks 0-3][h2: chunks 0-3], 16 pairs per chunk.
// Padded chunk stride 20 u32 kills the 4-way bank conflict.
__global__ __launch_bounds__(1024, 4) void k_l1(
    u32* __restrict__ hws,
    const float* __restrict__ Wih, const float* __restrict__ Whh,
    const float* __restrict__ bih, const float* __restrict__ bhh,
    float* __restrict__ out)
{
    __shared__ u32 h1w[128 * 80];  // 128-step h1 window, padded chunks (40KB)
    __shared__ u32 hp[2][80];      // h2 state double buffer, padded
    __shared__ u32 och[4096];      // 64-step h2 staging (16KB)

    const int tid = threadIdx.x, b = blockIdx.x;
    const int m = tid >> 3, ksl = tid & 7;

    u32 w[64];
    float bias[4];
    const float* Wsel = (ksl < 4) ? Wih : Whh;
    const int colb = (ksl & 3) * 32;
#pragma unroll
    for (int g = 0; g < 4; ++g) {
        const int row = g * H_ + m;
        const float4* wr_ = (const float4*)(Wsel + row * H_ + colb);
#pragma unroll
        for (int j = 0; j < 8; ++j) {
            const float4 f = wr_[j];
            w[g * 16 + 2 * j]     = packh2(f.x, f.y);
            w[g * 16 + 2 * j + 1] = packh2(f.z, f.w);
        }
        bias[g] = bih[row] + bhh[row];
    }

    if (tid < 160) ((u32*)hp)[tid] = 0u;
    float c = 0.f;
    __syncthreads();

    u32* hbase = hws + (size_t)b * S_ * 64;
    for (int u = 0; u < S_; ++u) {
        if ((u & 127) == 0) {                    // stage 128-step h1 window (padded)
            for (int i = tid; i < 2048; i += 1024) {
                const uint4 v = *(const uint4*)(hbase + (size_t)u * 64 + i * 4);
                const int st = i >> 4, p4 = i & 15;
                *(uint4*)(&h1w[st * 80 + (p4 >> 2) * 20 + (p4 & 3) * 4]) = v;
            }
            __syncthreads();
        }
        const u32* sel = (ksl < 4) ? &h1w[(u & 127) * 80 + ksl * 20]
                                   : &hp[(u + 1) & 1][(ksl - 4) * 20];
        float a0 = 0.f, a1 = 0.f, a2 = 0.f, a3 = 0.f;
#pragma unroll
        for (int p = 0; p < 4; ++p) {
            const uint4 v = *(const uint4*)(sel + p * 4);
            a0 = fdot2(v.x, w[4 * p], a0);      a0 = fdot2(v.y, w[4 * p + 1], a0);
            a0 = fdot2(v.z, w[4 * p + 2], a0);  a0 = fdot2(v.w, w[4 * p + 3], a0);
            a1 = fdot2(v.x, w[16 + 4 * p], a1); a1 = fdot2(v.y, w[17 + 4 * p], a1);
            a1 = fdot2(v.z, w[18 + 4 * p], a1); a1 = fdot2(v.w, w[19 + 4 * p], a1);
            a2 = fdot2(v.x, w[32 + 4 * p], a2); a2 = fdot2(v.y, w[33 + 4 * p], a2);
            a2 = fdot2(v.z, w[34 + 4 * p], a2); a2 = fdot2(v.w, w[35 + 4 * p], a2);
            a3 = fdot2(v.x, w[48 + 4 * p], a3); a3 = fdot2(v.y, w[49 + 4 * p], a3);
            a3 = fdot2(v.z, w[50 + 4 * p], a3); a3 = fdot2(v.w, w[51 + 4 * p], a3);
        }
        REDUCE8(a0) REDUCE8(a1) REDUCE8(a2) REDUCE8(a3)
        const float ig = sigm(a0 + bias[0]);
        const float fg = sigm(a1 + bias[1]);
        const float gc = tanh_(a2 + bias[2]);
        const float og = sigm(a3 + bias[3]);
        c = fg * c + ig * gc;
        const float hv = og * tanh_(c);
        const u32 pp = packh2(hv, __shfl_xor(hv, 8));
        if ((tid & 15) == 0) {
            const int m2 = m >> 1;
            hp[u & 1][(m2 >> 4) * 20 + (m2 & 15)] = pp;
            och[(u & 63) * 64 + m2] = pp;
        }
        if (u == S_ - 1 && (tid & 7) == 0) {
            out[HH0 + 32768 + (size_t)b * H_ + m] = hv;
            out[HC0 + 32768 + (size_t)b * H_ + m] = c;
        }
        __syncthreads();
        if ((u & 63) == 63) {                    // flush h2 rows (in-place over h1)
            u32* dst = hbase + (size_t)(u - 63) * 64;
            *(uint4*)(dst + tid * 4) = *(const uint4*)(&och[tid * 4]);
            __syncthreads();
        }
    }
}

// ===================== heads: parallel over (b,s) ===========================
__global__ __launch_bounds__(256) void k_heads(
    const u32* __restrict__ h2p,
    const float* __restrict__ Wr1, const float* __restrict__ br1,
    const float* __restrict__ Wr2, const float* __restrict__ br2,
    const float* __restrict__ Wv1, const float* __restrict__ bv1,
    const float* __restrict__ Wv2, const float* __restrict__ bv2,
    float* __restrict__ out)
{
    __shared__ u32 wr[64 * 64], wv[64 * 64];   // W1 pairs (16KB each)
    __shared__ float w2r[64], w2v[64], b1r[64], b1v[64];

    const int tid = threadIdx.x;
    for (int i = tid; i < 4096; i += 256) {
        wr[i] = packh2(Wr1[2 * i], Wr1[2 * i + 1]);
        wv[i] = packh2(Wv1[2 * i], Wv1[2 * i + 1]);
    }
    if (tid < 64) {
        w2r[tid] = Wr2[tid]; w2v[tid] = Wv2[tid];
        b1r[tid] = br1[tid]; b1v[tid] = bv1[tid];
    }
    __syncthreads();

    const size_t bs = (size_t)blockIdx.x * 256 + tid;   // (b,s) flat
    u32 hq[64];
    const u32* src = h2p + bs * 64;
#pragma unroll
    for (int j4 = 0; j4 < 16; ++j4) {
        const uint4 v = *(const uint4*)(src + j4 * 4);
        hq[j4 * 4] = v.x; hq[j4 * 4 + 1] = v.y; hq[j4 * 4 + 2] = v.z; hq[j4 * 4 + 3] = v.w;
    }
    float ret = br2[0], vol = bv2[0];
    for (int k = 0; k < 64; ++k) {
        float r = b1r[k], v = b1v[k];
#pragma unroll
        for (int j = 0; j < 64; ++j) r = fdot2(hq[j], wr[k * 64 + j], r);
#pragma unroll
        for (int j = 0; j < 64; ++j) v = fdot2(hq[j], wv[k * 64 + j], v);
        r = r > 0.f ? r : 0.01f * r;
        v = v > 0.f ? v : 0.01f * v;
        ret += r * w2r[k];
        vol += v * w2v[k];
    }
    out[RET0 + bs] = ret;
    out[VOL0 + bs] = softplus_(vol);
}

extern "C" void kernel_launch(void* const* d_in, const int* in_sizes, int n_in,
                              void* d_out, int out_size, void* d_ws, size_t ws_size,
                              hipStream_t stream) {
    (void)in_sizes; (void)n_in; (void)out_size; (void)ws_size;
    const float* x    = (const float*)d_in[0];
    const float* Wih0 = (const float*)d_in[1];
    const float* Whh0 = (const float*)d_in[2];
    const float* bih0 = (const float*)d_in[3];
    const float* bhh0 = (const float*)d_in[4];
    const float* Wih1 = (const float*)d_in[5];
    const float* Whh1 = (const float*)d_in[6];
    const float* bih1 = (const float*)d_in[7];
    const float* bhh1 = (const float*)d_in[8];
    const float* Wr1  = (const float*)d_in[9];
    const float* br1  = (const float*)d_in[10];
    const float* Wr2  = (const float*)d_in[11];
    const float* br2  = (const float*)d_in[12];
    const float* Wv1  = (const float*)d_in[13];
    const float* bv1  = (const float*)d_in[14];
    const float* Wv2  = (const float*)d_in[15];
    const float* bv2  = (const float*)d_in[16];
    u32* hws = (u32*)d_ws;            // 256*2048*64 u32 = 134MB (h1, then h2 in-place)
    float* out = (float*)d_out;

    k_l0<<<B_, 1024, 0, stream>>>(x, Wih0, Whh0, bih0, bhh0, hws, out);
    k_l1<<<B_, 1024, 0, stream>>>(hws, Wih1, Whh1, bih1, bhh1, out);
    k_heads<<<2048, 256, 0, stream>>>(hws, Wr1, br1, Wr2, br2, Wv1, bv1, Wv2, bv2, out);
}